// Round 6
// baseline (5801.064 us; speedup 1.0000x reference)
//
#include <hip/hip_runtime.h>
#include <math.h>

#define NTOK   16384
#define DMODEL 4096
#define NEXP   64
#define NWAVE  4                 // waves per block
#define TOKW   8                 // tokens per wave (lane = expert)
#define TOKB   (NWAVE * TOKW)    // 32 tokens per block -> grid 512 = 2 blocks/CU
#define KC     64                // k-chunk per iteration
#define NCH    (DMODEL / KC)     // 64 chunks

#define LD4(p) (*(const float4*)(p))

// lane = expert: W[k][e] loads are coalesced vector loads (off the scalar path,
// L1-hot across the 8 waves/CU). x[t][k] broadcast via wave-private LDS tile +
// uniform ds_read_b128. Accumulation is blocked-serial-ascending in k (chunk-
// internal strict fmaf chain, chunk partials added in ascending order) to stay
// numerically correlated with the BLAS-style reference — round 4's interleaved
// chains caused a near-tie top-2 index flip.

// one chunk: stage x, prefetch x & W(next), compute serial-in-k into cp[], fold
#define CHUNK_STEP(c, WCUR, WNXT, LASTP)  do {                                 \
    *(float4*)(xt + sofs)     = pa;                                            \
    *(float4*)(xt + sofs + 4) = pb;                                            \
    if (!(LASTP)) {                                                            \
        const float* np_ = sp + (size_t)((c) + 1) * KC;                        \
        pa = LD4(np_); pb = LD4(np_ + 4);                                      \
        const float* wp_ = W + (size_t)((c) + 1) * KC * NEXP + lane;           \
        _Pragma("unroll")                                                      \
        for (int kc = 0; kc < KC; ++kc) WNXT[kc] = wp_[(size_t)kc * NEXP];     \
    }                                                                          \
    float cp[TOKW];                                                            \
    _Pragma("unroll")                                                          \
    for (int t = 0; t < TOKW; ++t) cp[t] = 0.f;                                \
    _Pragma("unroll")                                                          \
    for (int q = 0; q < KC / 4; ++q) {                                         \
        _Pragma("unroll")                                                      \
        for (int t = 0; t < TOKW; ++t) {                                       \
            const float4 xv = *(const float4*)(xt + t * KC + q * 4);           \
            cp[t] = fmaf(WCUR[q * 4 + 3], xv.w,                                \
                    fmaf(WCUR[q * 4 + 2], xv.z,                                \
                    fmaf(WCUR[q * 4 + 1], xv.y,                                \
                    fmaf(WCUR[q * 4 + 0], xv.x, cp[t]))));                     \
        }                                                                      \
    }                                                                          \
    _Pragma("unroll")                                                          \
    for (int t = 0; t < TOKW; ++t) acc[t] += cp[t];                            \
} while (0)

__global__ __launch_bounds__(NWAVE * 64, 2)
void router_kernel(const float* __restrict__ x,
                   const float* __restrict__ W,
                   const float* __restrict__ b,
                   float* __restrict__ out)
{
    __shared__ __align__(16) float xs[NWAVE][TOKW * KC];   // 8 KB, wave-private tiles
    __shared__ float ls[TOKB][NEXP + 1];                   // 8.3 KB, padded: conflict-free

    const int tid  = threadIdx.x;
    const int lane = tid & 63;
    const int wid  = tid >> 6;
    const int t0   = blockIdx.x * TOKB + wid * TOKW;

    // staging map: lane l stages 32 B of token (l>>3), k-offset (l&7)*8
    const int    st   = lane >> 3;
    const int    sk   = (lane & 7) * 8;
    const float* sp   = x + (size_t)(t0 + st) * DMODEL + sk;
    const int    sofs = st * KC + sk;

    float* xt = &xs[wid][0];

    float acc[TOKW];
#pragma unroll
    for (int t = 0; t < TOKW; ++t) acc[t] = 0.f;

    // prologue: x chunk 0 and W chunk 0
    float4 pa = LD4(sp), pb = LD4(sp + 4);
    float wA[KC], wB[KC];
    {
        const float* wp_ = W + lane;
#pragma unroll
        for (int kc = 0; kc < KC; ++kc) wA[kc] = wp_[(size_t)kc * NEXP];
    }

    for (int c = 0; c < NCH; c += 2) {
        CHUNK_STEP(c,     wA, wB, false);
        CHUNK_STEP(c + 1, wB, wA, (c + 2 == NCH));
    }

    // logits -> LDS, transposed to [token][expert] with +1 pad
#pragma unroll
    for (int t = 0; t < TOKW; ++t) ls[wid * TOKW + t][lane] = acc[t];
    __syncthreads();

    // verified epilogue (rounds 0-3 semantics): one token per thread
    if (tid < TOKB) {
        const int t = blockIdx.x * TOKB + tid;
        float l[NEXP];
        float m = -INFINITY;
#pragma unroll
        for (int e = 0; e < NEXP; ++e) {
            l[e] = ls[tid][e] + b[e];
            m = fmaxf(m, l[e]);
        }
        float Z = 0.f;
#pragma unroll
        for (int e = 0; e < NEXP; ++e) {
            l[e] = expf(l[e] - m);
            Z += l[e];
        }
        // top-2 over probs, ties -> lower index (jax.lax.top_k semantics)
        float p1 = -1.f, p2 = -1.f;
        int i1 = 0, i2 = 0;
#pragma unroll
        for (int e = 0; e < NEXP; ++e) {
            const float p = l[e] / Z;
            if (p > p1) { p2 = p1; i2 = i1; p1 = p; i1 = e; }
            else if (p > p2) { p2 = p; i2 = e; }
        }
        const float s = p1 + p2;
        out[2 * t]     = p1 / s;
        out[2 * t + 1] = p2 / s;
        // indices written as float: harness reads the whole output as f32
        out[2 * NTOK + 2 * t]     = (float)i1;
        out[2 * NTOK + 2 * t + 1] = (float)i2;
    }
}

extern "C" void kernel_launch(void* const* d_in, const int* in_sizes, int n_in,
                              void* d_out, int out_size, void* d_ws, size_t ws_size,
                              hipStream_t stream) {
    const float* x = (const float*)d_in[0];
    const float* W = (const float*)d_in[1];
    const float* b = (const float*)d_in[2];
    float* out = (float*)d_out;
    router_kernel<<<dim3(NTOK / TOKB), dim3(NWAVE * 64), 0, stream>>>(x, W, b, out);
}